// Round 15
// baseline (306.259 us; speedup 1.0000x reference)
//
#include <hip/hip_runtime.h>

// Problem constants (fixed by the reference setup).
#define BATCH  256
#define SEQT   2048
#define LAYERS 4
#define CHUNK  16                        // timesteps per handoff chunk
#define NCHUNK (SEQT / CHUNK)            // 128 chunks per layer
#define HID    64
// P (input / projected hidden size) == 1

#define LOG2E  1.4426950408889634f
#define K2     (2.0f * LOG2E)            // c is carried as C = K2 * c

__device__ __forceinline__ float fast_rcp(float x) {
    return __builtin_amdgcn_rcpf(x);
}
__device__ __forceinline__ float fast_exp2(float x) {
    return __builtin_amdgcn_exp2f(x);    // raw v_exp_f32 (2^x)
}

// One DPP-shifted add: v += dpp_move(v). bound_ctrl=true -> invalid lanes read 0.
#define DPP_ADD(v, ctrl)                                                     \
    (v) += __int_as_float(__builtin_amdgcn_update_dpp(                       \
        0, __float_as_int(v), (ctrl), 0xF, 0xF, true))

// Full wave64 sum via DPP row reduce + row broadcasts; total lands in lane 63.
__device__ __forceinline__ float wave_sum_lane63(float v) {
    DPP_ADD(v, 0x111);   // row_shr:1
    DPP_ADD(v, 0x112);   // row_shr:2
    DPP_ADD(v, 0x114);   // row_shr:4
    DPP_ADD(v, 0x118);   // row_shr:8 -> lanes 15/31/47/63 = row sums
    DPP_ADD(v, 0x142);   // row_bcast:15
    DPP_ADD(v, 0x143);   // row_bcast:31 -> lane 63 = full sum
    return v;
}

// One block per batch element, 4 waves = 4 layers, 1 wave/SIMD (measured
// optimum: R6/R10/R11 showed every multi-chain packing is issue-additive --
// wave64 trans ops block issue ~16 cy each and dominate).
// ASYNC layer pipeline (R13): each inter-layer stream (2048 floats) lives
// entirely in LDS; producers never wait, consumers only during initial fill;
// handoff = volatile LDS chunk counter + __threadfence_block release/acquire.
// CHUNK=16: makespan = 2048 + 3*CHUNK slots (chunk-DAG critical path), so
// halving CHUNK cuts pipeline fill 96->48 slots at ~85 cy/extra-handoff --
// measured-model net win vs CHUNK=32 (R13: 2144 slots x 282 cy = 252 us, exact).
// Per step: 7 transcendentals (5 exp2 + 2 rcp -- algebraic floor), merged-rcp
// c-update, DPP reduce, cndmask collector, one masked LDS store per chunk.
__global__ __launch_bounds__(256, 1) void lstm_pipeline_kernel(
    const float* __restrict__ y,      // [B, T, 1]
    const float* __restrict__ W_ih,   // [L, 4H, 1]
    const float* __restrict__ W_hh,   // [L, 4H, 1]
    const float* __restrict__ b_ih,   // [L, 4H]
    const float* __restrict__ b_hh,   // [L, 4H]
    const float* __restrict__ W_hr,   // [L, 1, H]
    const int*  __restrict__ msl_p,   // min_seq_len scalar
    float* __restrict__ out)          // [B, T - msl, 1]
{
    const int b   = blockIdx.x;
    const int tid = threadIdx.x;
    const int l   = tid >> 6;   // layer / wave id
    const int k   = tid & 63;   // hidden unit / lane
    const int msl = *msl_p;

    __shared__ float y_lds[SEQT];                  //  8 KB: layer-0 input
    __shared__ float inter[LAYERS - 1][SEQT];      // 24 KB: inter-layer h streams
    __shared__ float out_lds[SEQT];                //  8 KB: final outputs
    __shared__ int   flags[LAYERS];                // chunks published per layer

    // Stage y[b, :] into LDS with float4 loads; init handoff flags.
    {
        const float4* y4  = (const float4*)(y + (size_t)b * SEQT);
        float4*       yl4 = (float4*)y_lds;
        #pragma unroll
        for (int i = tid; i < SEQT / 4; i += 256) yl4[i] = y4[i];
        if (tid < LAYERS) flags[tid] = 0;
    }

    // Loop-invariant weights. Gate order: i, f, g, o.
    // i, f, o carry -log2e (exp2 -> e^-gate); g carries 2*log2e (exp2 -> e^{2g}).
    const int wbase = l * 4 * HID;
    const float wi0 = -LOG2E * W_ih[wbase + 0 * HID + k];
    const float wi1 = -LOG2E * W_ih[wbase + 1 * HID + k];
    const float wi2 =  K2    * W_ih[wbase + 2 * HID + k];
    const float wi3 = -LOG2E * W_ih[wbase + 3 * HID + k];
    const float wh0 = -LOG2E * W_hh[wbase + 0 * HID + k];
    const float wh1 = -LOG2E * W_hh[wbase + 1 * HID + k];
    const float wh2 =  K2    * W_hh[wbase + 2 * HID + k];
    const float wh3 = -LOG2E * W_hh[wbase + 3 * HID + k];
    const float bb0 = -LOG2E * (b_ih[wbase + 0 * HID + k] + b_hh[wbase + 0 * HID + k]);
    const float bb1 = -LOG2E * (b_ih[wbase + 1 * HID + k] + b_hh[wbase + 1 * HID + k]);
    const float bb2 =  K2    * (b_ih[wbase + 2 * HID + k] + b_hh[wbase + 2 * HID + k]);
    const float bb3 = -LOG2E * (b_ih[wbase + 3 * HID + k] + b_hh[wbase + 3 * HID + k]);
    const float wr  = W_hr[l * HID + k];

    __syncthreads();   // y_lds + flags visible (the ONLY mid-kernel barrier)

    float h = 0.0f;   // projected hidden (wave-uniform)
    float C = 0.0f;   // cell state, scaled: C = 2*log2e*c

    volatile int* vflags = flags;

    for (int c = 0; c < NCHUNK; ++c) {
        const int t0 = c * CHUNK;

        // Acquire: wait until layer l-1 has published chunk c (steady state:
        // falls through immediately; producers never wait -- full-seq buffer).
        if (l > 0) {
            while (vflags[l - 1] <= c) __builtin_amdgcn_s_sleep(1);
            __threadfence_block();
        }

        // Fetch this chunk's 16 scalar inputs (wave-uniform broadcast reads).
        const float* src = (l == 0) ? &y_lds[t0] : &inter[l - 1][t0];
        float4 xv[CHUNK / 4];
        {
            const float4* s4 = (const float4*)src;
            #pragma unroll
            for (int q = 0; q < CHUNK / 4; ++q) xv[q] = s4[q];
        }
        float xs[CHUNK];
        #pragma unroll
        for (int q = 0; q < CHUNK / 4; ++q) {
            xs[4 * q + 0] = xv[q].x; xs[4 * q + 1] = xv[q].y;
            xs[4 * q + 2] = xv[q].z; xs[4 * q + 3] = xv[q].w;
        }

        // Input-side gate contributions: independent of h, off the chain
        // (the list scheduler interleaves these into chain stall shadows --
        // verified optimal vs forced rolling placement, R14).
        float p0[CHUNK], p1[CHUNK], p2[CHUNK], p3[CHUNK];
        #pragma unroll
        for (int j = 0; j < CHUNK; ++j) {
            p0[j] = fmaf(xs[j], wi0, bb0);
            p1[j] = fmaf(xs[j], wi1, bb1);
            p2[j] = fmaf(xs[j], wi2, bb2);
            p3[j] = fmaf(xs[j], wi3, bb3);
        }

        // Collector: lane j ends up holding step j's h (branch-free select).
        float hcol = 0.0f;

        #pragma unroll
        for (int j = 0; j < CHUNK; ++j) {
            // Gate pre-activations (scales pre-folded into weights).
            const float gi = fmaf(h, wh0, p0[j]);
            const float gf = fmaf(h, wh1, p1[j]);
            const float gg = fmaf(h, wh2, p2[j]);
            const float go = fmaf(h, wh3, p3[j]);

            const float Ei = fast_exp2(gi);     // e^-i
            const float Ef = fast_exp2(gf);     // e^-f
            const float Eg = fast_exp2(gg);     // e^{2g}
            const float Eo = fast_exp2(go);     // e^-o

            // Merged c-update: one rcp for sf*C + si*tanh(g)*K2.
            const float ai     = 1.0f + Ei;
            const float ag     = 1.0f + Eg;
            const float af     = 1.0f + Ef;
            const float den_ig = ai * ag;
            const float tg     = fmaf(K2, Eg, -K2);   // K2(Eg-1)
            const float tgf    = tg * af;             // K2(Eg-1)(1+Ef)
            const float num    = fmaf(C, den_ig, tgf);
            const float den    = den_ig * af;
            C = num * fast_rcp(den);

            // Output: v = wr(Ec-1)/((1+Eo)(1+Ec)), one rcp.
            const float Ec   = fast_exp2(C);          // e^{2c}
            const float ao   = 1.0f + Eo;
            const float ac   = 1.0f + Ec;
            const float den2 = ao * ac;
            const float num2 = fmaf(wr, Ec, -wr);     // wr(Ec-1)
            const float v    = num2 * fast_rcp(den2);

            const float vs = wave_sum_lane63(v);      // lane 63 = sum

            // Wave-uniform h for the next step (readlane -> SGPR).
            h = __int_as_float(
                __builtin_amdgcn_readlane(__float_as_int(vs), 63));

            // Deposit into lane j of the collector -- no branch.
            hcol = (k == j) ? h : hcol;
        }

        // Publish chunk c (lanes 0..15 hold steps 0..15).
        if (l < LAYERS - 1) {
            if (k < CHUNK) inter[l][t0 + k] = hcol;
            __threadfence_block();                 // release: data before flag
            if (k == 0) vflags[l] = c + 1;
        } else {
            if (k < CHUNK) out_lds[t0 + k] = hcol; // no consumer to signal
        }
    }

    // Flush buffered outputs to global once (coalesced).
    __syncthreads();
    const int nout = SEQT - msl;
    float* outb = out + (size_t)b * nout;
    for (int i = tid; i < nout; i += 256) outb[i] = out_lds[i + msl];
}

extern "C" void kernel_launch(void* const* d_in, const int* in_sizes, int n_in,
                              void* d_out, int out_size, void* d_ws, size_t ws_size,
                              hipStream_t stream) {
    const float* y    = (const float*)d_in[0];
    const float* W_ih = (const float*)d_in[1];
    const float* W_hh = (const float*)d_in[2];
    const float* b_ih = (const float*)d_in[3];
    const float* b_hh = (const float*)d_in[4];
    const float* W_hr = (const float*)d_in[5];
    const int*   msl  = (const int*)d_in[6];
    float* out = (float*)d_out;

    lstm_pipeline_kernel<<<BATCH, 256, 0, stream>>>(
        y, W_ih, W_hh, b_ih, b_hh, W_hr, msl, out);
}

// Round 16
// 297.835 us; speedup vs baseline: 1.0283x; 1.0283x over previous
//
#include <hip/hip_runtime.h>

// Problem constants (fixed by the reference setup).
#define BATCH  256
#define SEQT   2048
#define LAYERS 4
#define CHUNK  32                        // timesteps per handoff chunk (measured optimum, R13 vs R15)
#define HALF   16                        // precompute granularity (VGPR cap)
#define NCHUNK (SEQT / CHUNK)            // 64 chunks per layer
#define HID    64
// P (input / projected hidden size) == 1

#define LOG2E  1.4426950408889634f
#define K2     (2.0f * LOG2E)            // c is carried as C = K2 * c

__device__ __forceinline__ float fast_rcp(float x) {
    return __builtin_amdgcn_rcpf(x);
}
__device__ __forceinline__ float fast_exp2(float x) {
    return __builtin_amdgcn_exp2f(x);    // raw v_exp_f32 (2^x)
}

// One DPP-shifted add: v += dpp_move(v). bound_ctrl=true -> invalid lanes read 0.
#define DPP_ADD(v, ctrl)                                                     \
    (v) += __int_as_float(__builtin_amdgcn_update_dpp(                       \
        0, __float_as_int(v), (ctrl), 0xF, 0xF, true))

// Full wave64 sum via DPP row reduce + row broadcasts; total lands in lane 63.
__device__ __forceinline__ float wave_sum_lane63(float v) {
    DPP_ADD(v, 0x111);   // row_shr:1
    DPP_ADD(v, 0x112);   // row_shr:2
    DPP_ADD(v, 0x114);   // row_shr:4
    DPP_ADD(v, 0x118);   // row_shr:8 -> lanes 15/31/47/63 = row sums
    DPP_ADD(v, 0x142);   // row_bcast:15
    DPP_ADD(v, 0x143);   // row_bcast:31 -> lane 63 = full sum
    return v;
}

// MEASURED-OPTIMUM kernel (R13 structure, 252 us / 282 cy-per-step):
// One block per batch element, 4 waves = 4 layers, 1 wave/SIMD (R6/R10/R11:
// every multi-chain packing is issue-additive -- wave64 trans ops block issue
// ~16 cy each -- so N chains/SIMD costs N x 192 cy/step > single-chain wall).
// ASYNC layer pipeline: each inter-layer stream (2048 floats) lives entirely
// in LDS; producers never wait (no back-pressure), consumers only during
// initial fill; handoff = volatile LDS chunk counter + __threadfence_block
// release/acquire. No per-phase __syncthreads (R12->R13: ~500 cy/barrier).
// Per step: 7 transcendentals (5 exp2 + 2 rcp -- algebraic floor), merged-rcp
// c-update, DPP reduce + readlane, cndmask collector, one masked LDS store
// per chunk. Wall = issue floor (~192 cy: 7 trans x 16 + ~31 VALU x 2)
// + ~90 cy exposed recurrence latency the in-order stream cannot fill
// (verified: rolling precompute R14 and CHUNK=16 R15 both regress).
__global__ __launch_bounds__(256, 1) void lstm_pipeline_kernel(
    const float* __restrict__ y,      // [B, T, 1]
    const float* __restrict__ W_ih,   // [L, 4H, 1]
    const float* __restrict__ W_hh,   // [L, 4H, 1]
    const float* __restrict__ b_ih,   // [L, 4H]
    const float* __restrict__ b_hh,   // [L, 4H]
    const float* __restrict__ W_hr,   // [L, 1, H]
    const int*  __restrict__ msl_p,   // min_seq_len scalar
    float* __restrict__ out)          // [B, T - msl, 1]
{
    const int b   = blockIdx.x;
    const int tid = threadIdx.x;
    const int l   = tid >> 6;   // layer / wave id
    const int k   = tid & 63;   // hidden unit / lane
    const int msl = *msl_p;

    __shared__ float y_lds[SEQT];                  //  8 KB: layer-0 input
    __shared__ float inter[LAYERS - 1][SEQT];      // 24 KB: inter-layer h streams
    __shared__ float out_lds[SEQT];                //  8 KB: final outputs
    __shared__ int   flags[LAYERS];                // chunks published per layer

    // Stage y[b, :] into LDS with float4 loads; init handoff flags.
    {
        const float4* y4  = (const float4*)(y + (size_t)b * SEQT);
        float4*       yl4 = (float4*)y_lds;
        #pragma unroll
        for (int i = tid; i < SEQT / 4; i += 256) yl4[i] = y4[i];
        if (tid < LAYERS) flags[tid] = 0;
    }

    // Loop-invariant weights. Gate order: i, f, g, o.
    // i, f, o carry -log2e (exp2 -> e^-gate); g carries 2*log2e (exp2 -> e^{2g}).
    const int wbase = l * 4 * HID;
    const float wi0 = -LOG2E * W_ih[wbase + 0 * HID + k];
    const float wi1 = -LOG2E * W_ih[wbase + 1 * HID + k];
    const float wi2 =  K2    * W_ih[wbase + 2 * HID + k];
    const float wi3 = -LOG2E * W_ih[wbase + 3 * HID + k];
    const float wh0 = -LOG2E * W_hh[wbase + 0 * HID + k];
    const float wh1 = -LOG2E * W_hh[wbase + 1 * HID + k];
    const float wh2 =  K2    * W_hh[wbase + 2 * HID + k];
    const float wh3 = -LOG2E * W_hh[wbase + 3 * HID + k];
    const float bb0 = -LOG2E * (b_ih[wbase + 0 * HID + k] + b_hh[wbase + 0 * HID + k]);
    const float bb1 = -LOG2E * (b_ih[wbase + 1 * HID + k] + b_hh[wbase + 1 * HID + k]);
    const float bb2 =  K2    * (b_ih[wbase + 2 * HID + k] + b_hh[wbase + 2 * HID + k]);
    const float bb3 = -LOG2E * (b_ih[wbase + 3 * HID + k] + b_hh[wbase + 3 * HID + k]);
    const float wr  = W_hr[l * HID + k];

    __syncthreads();   // y_lds + flags visible (the ONLY mid-kernel barrier)

    float h = 0.0f;   // projected hidden (wave-uniform)
    float C = 0.0f;   // cell state, scaled: C = 2*log2e*c

    volatile int* vflags = flags;

    for (int c = 0; c < NCHUNK; ++c) {
        const int t0 = c * CHUNK;

        // Acquire: wait until layer l-1 has published chunk c (steady state:
        // falls through immediately; producers never wait -- full-seq buffer).
        if (l > 0) {
            while (vflags[l - 1] <= c) __builtin_amdgcn_s_sleep(1);
            __threadfence_block();
        }

        // Fetch this chunk's 32 scalar inputs (wave-uniform broadcast reads).
        const float* src = (l == 0) ? &y_lds[t0] : &inter[l - 1][t0];
        float4 xv[CHUNK / 4];
        {
            const float4* s4 = (const float4*)src;
            #pragma unroll
            for (int q = 0; q < CHUNK / 4; ++q) xv[q] = s4[q];
        }
        float xs[CHUNK];
        #pragma unroll
        for (int q = 0; q < CHUNK / 4; ++q) {
            xs[4 * q + 0] = xv[q].x; xs[4 * q + 1] = xv[q].y;
            xs[4 * q + 2] = xv[q].z; xs[4 * q + 3] = xv[q].w;
        }

        // Collector: lane j ends up holding step j's h (branch-free select).
        float hcol = 0.0f;

        // Two 16-step halves per chunk (precompute arrays sized HALF to cap
        // VGPR pressure; the list scheduler interleaves these into chain
        // stall shadows -- verified optimal vs forced rolling placement, R14).
        #pragma unroll
        for (int half = 0; half < CHUNK / HALF; ++half) {
            const int jb = half * HALF;

            // Input-side gate contributions: independent of h, off chain.
            float p0[HALF], p1[HALF], p2[HALF], p3[HALF];
            #pragma unroll
            for (int j = 0; j < HALF; ++j) {
                const float x = xs[jb + j];
                p0[j] = fmaf(x, wi0, bb0);
                p1[j] = fmaf(x, wi1, bb1);
                p2[j] = fmaf(x, wi2, bb2);
                p3[j] = fmaf(x, wi3, bb3);
            }

            #pragma unroll
            for (int j = 0; j < HALF; ++j) {
                // Gate pre-activations (scales pre-folded into weights).
                const float gi = fmaf(h, wh0, p0[j]);
                const float gf = fmaf(h, wh1, p1[j]);
                const float gg = fmaf(h, wh2, p2[j]);
                const float go = fmaf(h, wh3, p3[j]);

                const float Ei = fast_exp2(gi);     // e^-i
                const float Ef = fast_exp2(gf);     // e^-f
                const float Eg = fast_exp2(gg);     // e^{2g}
                const float Eo = fast_exp2(go);     // e^-o

                // Merged c-update: one rcp for sf*C + si*tanh(g)*K2.
                const float ai     = 1.0f + Ei;
                const float ag     = 1.0f + Eg;
                const float af     = 1.0f + Ef;
                const float den_ig = ai * ag;
                const float tg     = fmaf(K2, Eg, -K2);   // K2(Eg-1)
                const float tgf    = tg * af;             // K2(Eg-1)(1+Ef)
                const float num    = fmaf(C, den_ig, tgf);
                const float den    = den_ig * af;
                C = num * fast_rcp(den);

                // Output: v = wr(Ec-1)/((1+Eo)(1+Ec)), one rcp.
                const float Ec   = fast_exp2(C);          // e^{2c}
                const float ao   = 1.0f + Eo;
                const float ac   = 1.0f + Ec;
                const float den2 = ao * ac;
                const float num2 = fmaf(wr, Ec, -wr);     // wr(Ec-1)
                const float v    = num2 * fast_rcp(den2);

                const float vs = wave_sum_lane63(v);      // lane 63 = sum

                // Wave-uniform h for the next step (readlane -> SGPR).
                h = __int_as_float(
                    __builtin_amdgcn_readlane(__float_as_int(vs), 63));

                // Deposit into lane (jb+j) of the collector -- no branch.
                hcol = (k == jb + j) ? h : hcol;
            }
        }

        // Publish chunk c (lanes 0..31 hold steps 0..31).
        if (l < LAYERS - 1) {
            if (k < CHUNK) inter[l][t0 + k] = hcol;
            __threadfence_block();                 // release: data before flag
            if (k == 0) vflags[l] = c + 1;
        } else {
            if (k < CHUNK) out_lds[t0 + k] = hcol; // no consumer to signal
        }
    }

    // Flush buffered outputs to global once (coalesced).
    __syncthreads();
    const int nout = SEQT - msl;
    float* outb = out + (size_t)b * nout;
    for (int i = tid; i < nout; i += 256) outb[i] = out_lds[i + msl];
}

extern "C" void kernel_launch(void* const* d_in, const int* in_sizes, int n_in,
                              void* d_out, int out_size, void* d_ws, size_t ws_size,
                              hipStream_t stream) {
    const float* y    = (const float*)d_in[0];
    const float* W_ih = (const float*)d_in[1];
    const float* W_hh = (const float*)d_in[2];
    const float* b_ih = (const float*)d_in[3];
    const float* b_hh = (const float*)d_in[4];
    const float* W_hr = (const float*)d_in[5];
    const int*   msl  = (const int*)d_in[6];
    float* out = (float*)d_out;

    lstm_pipeline_kernel<<<BATCH, 256, 0, stream>>>(
        y, W_ih, W_hh, b_ih, b_hh, W_hr, msl, out);
}